// Round 2
// baseline (890.060 us; speedup 1.0000x reference)
//
#include <hip/hip_runtime.h>
#include <stdint.h>

typedef unsigned short ushort_t;
typedef uint32_t u32;
typedef __bf16 bf16;
typedef bf16 bf16x8 __attribute__((ext_vector_type(8)));
typedef float f32x4 __attribute__((ext_vector_type(4)));
typedef ushort_t ushort8 __attribute__((ext_vector_type(8)));

__device__ __forceinline__ float b2f(ushort_t u) {
    u32 x = ((u32)u) << 16;
    return __builtin_bit_cast(float, x);
}
__device__ __forceinline__ ushort_t f2b(float f) {
    bf16 h = (bf16)f;
    return __builtin_bit_cast(ushort_t, h);
}
__device__ __forceinline__ float sigmoidf_(float x) { return 1.0f / (1.0f + __expf(-x)); }
__device__ __forceinline__ float tanhf_(float x) { return 1.0f - 2.0f / (1.0f + __expf(2.0f * x)); }

// load 8 consecutive fp32, round-to-nearest to bf16, return packed ushort8
__device__ __forceinline__ ushort8 cvt8(const float* __restrict__ p) {
    float4 v0 = *(const float4*)p;
    float4 v1 = *(const float4*)(p + 4);
    ushort8 r;
    r[0] = f2b(v0.x); r[1] = f2b(v0.y); r[2] = f2b(v0.z); r[3] = f2b(v0.w);
    r[4] = f2b(v1.x); r[5] = f2b(v1.y); r[6] = f2b(v1.z); r[7] = f2b(v1.w);
    return r;
}

// ---------------------------------------------------------------------------
// GEMM: C[M][1536] = A[M][K] @ [WF;WB]^T + [bF;bB]  (A,W,b fp32; C bf16).
// A row optionally gathered via tokens. 128x128 tile, 256 thr, bf16 MFMA.
// ---------------------------------------------------------------------------
#define TPAD 40  // LDS tile row stride (bf16): 32 data + 8 pad

__global__ __launch_bounds__(256) void gemm_xg(
    const float* __restrict__ A, const int* __restrict__ tok,
    const float* __restrict__ WF, const float* __restrict__ WB,
    const float* __restrict__ bF, const float* __restrict__ bB,
    ushort_t* __restrict__ C, int K)
{
    __shared__ ushort_t aT[128 * TPAD];
    __shared__ ushort_t bT[128 * TPAD];
    const int tid = threadIdx.x;
    const int lane = tid & 63, wv = tid >> 6;
    const int bn0 = blockIdx.x * 128;
    const int rm0 = blockIdx.y * 128;
    const int wm = (wv & 1) * 64, wn = (wv >> 1) * 64;

    f32x4 acc[4][4];
    f32x4 zero = {0.f, 0.f, 0.f, 0.f};
#pragma unroll
    for (int i = 0; i < 4; i++)
#pragma unroll
        for (int j = 0; j < 4; j++) acc[i][j] = zero;

    const int sr = tid >> 1;          // staged row 0..127
    const int sk = (tid & 1) * 16;    // k offset 0/16
    long arow = tok ? (long)tok[rm0 + sr] : (long)(rm0 + sr);
    const float* aSrc = A + arow * K + sk;
    int ng = bn0 + sr;
    const float* bSrc = (ng < 768 ? WF + (long)ng * K : WB + (long)(ng - 768) * K) + sk;

    const int nkc = K / 32;
    const int fm = lane & 15, fq = (lane >> 4) * 8;
    for (int kc = 0; kc < nkc; ++kc) {
        ushort8 av0 = cvt8(aSrc + kc * 32);
        ushort8 av1 = cvt8(aSrc + kc * 32 + 8);
        ushort8 bv0 = cvt8(bSrc + kc * 32);
        ushort8 bv1 = cvt8(bSrc + kc * 32 + 8);
        __syncthreads();
        *(ushort8*)(aT + sr * TPAD + sk) = av0;
        *(ushort8*)(aT + sr * TPAD + sk + 8) = av1;
        *(ushort8*)(bT + sr * TPAD + sk) = bv0;
        *(ushort8*)(bT + sr * TPAD + sk + 8) = bv1;
        __syncthreads();
        bf16x8 af[4], bfg[4];
#pragma unroll
        for (int i = 0; i < 4; i++)
            af[i] = __builtin_bit_cast(bf16x8, *(const ushort8*)(aT + (wm + i * 16 + fm) * TPAD + fq));
#pragma unroll
        for (int j = 0; j < 4; j++)
            bfg[j] = __builtin_bit_cast(bf16x8, *(const ushort8*)(bT + (wn + j * 16 + fm) * TPAD + fq));
#pragma unroll
        for (int i = 0; i < 4; i++)
#pragma unroll
            for (int j = 0; j < 4; j++)
                acc[i][j] = __builtin_amdgcn_mfma_f32_16x16x32_bf16(af[i], bfg[j], acc[i][j], 0, 0, 0);
    }
    const int fr0 = (lane >> 4) * 4;
#pragma unroll
    for (int j = 0; j < 4; j++) {
        int col = bn0 + wn + j * 16 + fm;
        float bias = (col < 768) ? bF[col] : bB[col - 768];
#pragma unroll
        for (int i = 0; i < 4; i++) {
#pragma unroll
            for (int r = 0; r < 4; r++) {
                int row = rm0 + wm + i * 16 + fr0 + r;
                C[(long)row * 1536 + col] = f2b(acc[i][j][r] + bias);
            }
        }
    }
}

// ---------------------------------------------------------------------------
// Register-persistent bi-GRU level. 512 threads = 8 waves; wave w holds the
// 96 gate-rows [w*96, w*96+96) of Whh as bf16 MFMA B-fragments (192 VGPR).
// h: fp32 in updating threads' registers, bf16 copy in LDS for MFMA A-frags.
// grid = 2 * (nSentTotal/NS); blockIdx&1 = direction.
// PyTorch gate order r,z,n; n = tanh(xn + r*(h@Whh_n^T + bhh_n)).
// ---------------------------------------------------------------------------
#define HBS 264   // hbf row stride (bf16): 256 + 8 pad
#define HGS 770   // hg row stride (fp32): 768 + 2 pad

__global__ __launch_bounds__(512, 2) void gru_level(
    const float* __restrict__ WhhF, const float* __restrict__ WhhB,
    const float* __restrict__ bhhF, const float* __restrict__ bhhB,
    const ushort_t* __restrict__ xg,   // [nSentTotal*T][1536] bf16 (F cols 0..767, B 768..1535)
    ushort_t* __restrict__ out,        // [nSentTotal*T][512] bf16 (F dims 0..255, B 256..511)
    int T, int NS)
{
    __shared__ ushort_t hbf[16 * HBS];
    __shared__ float hg[16 * HGS];
    __shared__ float bhh_l[768];

    const int tid = threadIdx.x, lane = tid & 63, wv = tid >> 6;
    const int dir = blockIdx.x & 1;
    const int grp = blockIdx.x >> 1;
    const float* Whh = dir ? WhhB : WhhF;
    const float* bhh = dir ? bhhB : bhhF;
    const int dirOff = dir * 768;

    const int n0 = wv * 96;
    const int fm = lane & 15, fq = (lane >> 4) * 8;

    // persistent weight fragments: B[k][n] = Whh[n][k], bf16
    bf16x8 wfrag[6][8];
#pragma unroll
    for (int j = 0; j < 6; ++j) {
        const float* wrow = Whh + (long)(n0 + j * 16 + fm) * 256 + fq;
#pragma unroll
        for (int kc = 0; kc < 8; ++kc)
            wfrag[j][kc] = __builtin_bit_cast(bf16x8, cvt8(wrow + kc * 32));
    }
    for (int i = tid; i < 768; i += 512) bhh_l[i] = bhh[i];
    for (int i = tid; i < 16 * HBS / 2; i += 512) ((u32*)hbf)[i] = 0u;

    // update-phase ownership: 2 consecutive h dims per thread
    const int e0 = tid * 2;
    const int um = e0 >> 8;      // sentence-in-block
    const int ud = e0 & 255;     // dim
    const bool upd = (e0 < NS * 256);
    float h0 = 0.f, h1 = 0.f;
    const int s = grp * NS + um;
    const ushort_t* xgBase = xg + (long)s * T * 1536 + dirOff + ud;
    ushort_t* outBase = out + (long)s * T * 512 + dir * 256 + ud;
    __syncthreads();

    for (int st = 0; st < T; ++st) {
        const int tt = dir ? (T - 1 - st) : st;
        // ---- P1: hg = h @ Whh^T (wave's 96-column slice) ----
        f32x4 acc[6];
        f32x4 zero = {0.f, 0.f, 0.f, 0.f};
#pragma unroll
        for (int j = 0; j < 6; ++j) acc[j] = zero;
#pragma unroll
        for (int kc = 0; kc < 8; ++kc) {
            bf16x8 a = __builtin_bit_cast(bf16x8, *(const ushort8*)(hbf + fm * HBS + kc * 32 + fq));
#pragma unroll
            for (int j = 0; j < 6; ++j)
                acc[j] = __builtin_amdgcn_mfma_f32_16x16x32_bf16(a, wfrag[j][kc], acc[j], 0, 0, 0);
        }
        const int mr = (lane >> 4) * 4;
#pragma unroll
        for (int j = 0; j < 6; ++j) {
            int col = n0 + j * 16 + fm;
#pragma unroll
            for (int r = 0; r < 4; ++r) {
                int m = mr + r;
                if (m < NS) hg[m * HGS + col] = acc[j][r];
            }
        }
        __syncthreads();
        // ---- P2: gate nonlinearity + h update ----
        if (upd) {
            float hr0 = hg[um * HGS + ud] + bhh_l[ud];
            float hr1 = hg[um * HGS + ud + 1] + bhh_l[ud + 1];
            float hz0 = hg[um * HGS + 256 + ud] + bhh_l[256 + ud];
            float hz1 = hg[um * HGS + 256 + ud + 1] + bhh_l[256 + ud + 1];
            float hn0 = hg[um * HGS + 512 + ud] + bhh_l[512 + ud];
            float hn1 = hg[um * HGS + 512 + ud + 1] + bhh_l[512 + ud + 1];
            const ushort_t* xp = xgBase + (long)tt * 1536;
            u32 xr = *(const u32*)(xp);
            u32 xz = *(const u32*)(xp + 256);
            u32 xn = *(const u32*)(xp + 512);
            float r0 = sigmoidf_(b2f((ushort_t)xr) + hr0);
            float r1 = sigmoidf_(b2f((ushort_t)(xr >> 16)) + hr1);
            float z0 = sigmoidf_(b2f((ushort_t)xz) + hz0);
            float z1 = sigmoidf_(b2f((ushort_t)(xz >> 16)) + hz1);
            float nn0 = tanhf_(b2f((ushort_t)xn) + r0 * hn0);
            float nn1 = tanhf_(b2f((ushort_t)(xn >> 16)) + r1 * hn1);
            h0 = (1.f - z0) * nn0 + z0 * h0;
            h1 = (1.f - z1) * nn1 + z1 * h1;
            u32 hb = (u32)f2b(h0) | ((u32)f2b(h1) << 16);
            *(u32*)(hbf + um * HBS + ud) = hb;
            *(u32*)(outBase + (long)tt * 512) = hb;
        }
        __syncthreads();
    }
}

// ---------------------------------------------------------------------------
// Word attention: per sentence, scores=tanh(out.attW+b), softmax over 64 words,
// weighted sum -> sent_vecs[s][512] (fp32). 256 blocks x 256 threads.
// ---------------------------------------------------------------------------
__global__ void attn_word(const ushort_t* __restrict__ wout,
                          const float* __restrict__ attW,
                          const float* __restrict__ attB,
                          float* __restrict__ svec)
{
    __shared__ float part[64][4];
    __shared__ float aw[64];
    const int s = blockIdx.x, tid = threadIdx.x;
    const int w = tid >> 2, q = tid & 3;
    const ushort_t* row = wout + ((long)(s * 64 + w)) * 512 + q * 128;
    const float* ap = attW + q * 128;
    float sum = 0.f;
    for (int i = 0; i < 128; i += 8) {
        ushort8 a = *(const ushort8*)(row + i);
        float4 b0 = *(const float4*)(ap + i);
        float4 b1 = *(const float4*)(ap + i + 4);
        sum += b2f(a[0]) * b0.x + b2f(a[1]) * b0.y + b2f(a[2]) * b0.z + b2f(a[3]) * b0.w
             + b2f(a[4]) * b1.x + b2f(a[5]) * b1.y + b2f(a[6]) * b1.z + b2f(a[7]) * b1.w;
    }
    part[w][q] = sum;
    __syncthreads();
    if (tid < 64) {
        float sc = tanhf_(part[tid][0] + part[tid][1] + part[tid][2] + part[tid][3] + attB[0]);
        float m = sc;
#pragma unroll
        for (int o = 32; o >= 1; o >>= 1) m = fmaxf(m, __shfl_xor(m, o, 64));
        float e = __expf(sc - m);
        float se = e;
#pragma unroll
        for (int o = 32; o >= 1; o >>= 1) se += __shfl_xor(se, o, 64);
        aw[tid] = e / se;
    }
    __syncthreads();
    const int d = tid * 2;
    float a0 = 0.f, a1 = 0.f;
    const ushort_t* col = wout + ((long)(s * 64)) * 512 + d;
#pragma unroll 4
    for (int w2 = 0; w2 < 64; ++w2) {
        u32 v = *(const u32*)(col + (long)w2 * 512);
        float wg = aw[w2];
        a0 += wg * b2f((ushort_t)v);
        a1 += wg * b2f((ushort_t)(v >> 16));
    }
    *(float2*)(svec + (long)s * 512 + d) = make_float2(a0, a1);
}

// ---------------------------------------------------------------------------
// Sentence attention over 256 steps -> doc vec (fp32). 1 block x 256 threads.
// ---------------------------------------------------------------------------
__global__ void attn_sent(const ushort_t* __restrict__ sout,
                          const float* __restrict__ attW,
                          const float* __restrict__ attB,
                          float* __restrict__ doc)
{
    __shared__ float aw[256];
    __shared__ float red[8];
    const int tid = threadIdx.x;
    const ushort_t* row = sout + (long)tid * 512;
    float sum = 0.f;
    for (int i = 0; i < 512; i += 8) {
        ushort8 a = *(const ushort8*)(row + i);
        float4 b0 = *(const float4*)(attW + i);
        float4 b1 = *(const float4*)(attW + i + 4);
        sum += b2f(a[0]) * b0.x + b2f(a[1]) * b0.y + b2f(a[2]) * b0.z + b2f(a[3]) * b0.w
             + b2f(a[4]) * b1.x + b2f(a[5]) * b1.y + b2f(a[6]) * b1.z + b2f(a[7]) * b1.w;
    }
    float sc = tanhf_(sum + attB[0]);
    float m = sc;
#pragma unroll
    for (int o = 32; o >= 1; o >>= 1) m = fmaxf(m, __shfl_xor(m, o, 64));
    if ((tid & 63) == 0) red[tid >> 6] = m;
    __syncthreads();
    m = fmaxf(fmaxf(red[0], red[1]), fmaxf(red[2], red[3]));
    float e = __expf(sc - m);
    float se = e;
#pragma unroll
    for (int o = 32; o >= 1; o >>= 1) se += __shfl_xor(se, o, 64);
    if ((tid & 63) == 0) red[4 + (tid >> 6)] = se;
    __syncthreads();
    se = red[4] + red[5] + red[6] + red[7];
    aw[tid] = e / se;
    __syncthreads();
    const int d = tid * 2;
    float a0 = 0.f, a1 = 0.f;
    for (int t2 = 0; t2 < 256; ++t2) {
        u32 v = *(const u32*)(sout + (long)t2 * 512 + d);
        float w = aw[t2];
        a0 += w * b2f((ushort_t)v);
        a1 += w * b2f((ushort_t)(v >> 16));
    }
    doc[d] = a0;
    doc[d + 1] = a1;
}

// ---------------------------------------------------------------------------
// Classifier + softmax -> d_out[10] fp32. 1 wave.
// ---------------------------------------------------------------------------
__global__ void classify(const float* __restrict__ doc, const float* __restrict__ clsW,
                         const float* __restrict__ clsB, float* __restrict__ outp)
{
    const int lane = threadIdx.x;
    float logit = -1e30f;
    if (lane < 10) {
        float s = clsB[lane];
        const float* wr = clsW + lane * 512;
        for (int i = 0; i < 512; ++i) s += doc[i] * wr[i];
        logit = s;
    }
    float m = logit;
#pragma unroll
    for (int o = 32; o >= 1; o >>= 1) m = fmaxf(m, __shfl_xor(m, o, 64));
    float e = (lane < 10) ? __expf(logit - m) : 0.f;
    float se = e;
#pragma unroll
    for (int o = 32; o >= 1; o >>= 1) se += __shfl_xor(se, o, 64);
    if (lane < 10) outp[lane] = e / se;
}

extern "C" void kernel_launch(void* const* d_in, const int* in_sizes, int n_in,
                              void* d_out, int out_size, void* d_ws, size_t ws_size,
                              hipStream_t stream)
{
    const int*   tokens = (const int*)d_in[0];
    const float* emb    = (const float*)d_in[1];
    const float* wWihF  = (const float*)d_in[2];
    const float* wWhhF  = (const float*)d_in[3];
    const float* wBihF  = (const float*)d_in[4];
    const float* wBhhF  = (const float*)d_in[5];
    const float* wWihB  = (const float*)d_in[6];
    const float* wWhhB  = (const float*)d_in[7];
    const float* wBihB  = (const float*)d_in[8];
    const float* wBhhB  = (const float*)d_in[9];
    const float* sWihF  = (const float*)d_in[10];
    const float* sWhhF  = (const float*)d_in[11];
    const float* sBihF  = (const float*)d_in[12];
    const float* sBhhF  = (const float*)d_in[13];
    const float* sWihB  = (const float*)d_in[14];
    const float* sWhhB  = (const float*)d_in[15];
    const float* sBihB  = (const float*)d_in[16];
    const float* sBhhB  = (const float*)d_in[17];
    const float* wAttW  = (const float*)d_in[18];
    const float* wAttB  = (const float*)d_in[19];
    const float* sAttW  = (const float*)d_in[20];
    const float* sAttB  = (const float*)d_in[21];
    const float* clsW   = (const float*)d_in[22];
    const float* clsB   = (const float*)d_in[23];

    char* ws = (char*)d_ws;
    ushort_t* xg   = (ushort_t*)(ws);              // [16384][1536] bf16  50,331,648 B
    ushort_t* wout = (ushort_t*)(ws + 50331648);   // [16384][512]  bf16  16,777,216 B
    float*    svec = (float*)(ws + 67108864);      // [256][512]    fp32     524,288 B
    ushort_t* sxg  = (ushort_t*)(ws + 67633152);   // [256][1536]   bf16     786,432 B
    ushort_t* sout = (ushort_t*)(ws + 68419584);   // [256][512]    bf16     262,144 B
    float*    doc  = (float*)(ws + 68681728);      // [512]         fp32       2,048 B

    // word level
    gemm_xg<<<dim3(12, 128), 256, 0, stream>>>(emb, tokens, wWihF, wWihB, wBihF, wBihB, xg, 256);
    gru_level<<<128, 512, 0, stream>>>(wWhhF, wWhhB, wBhhF, wBhhB, xg, wout, 64, 4);
    attn_word<<<256, 256, 0, stream>>>(wout, wAttW, wAttB, svec);
    // sentence level
    gemm_xg<<<dim3(12, 2), 256, 0, stream>>>(svec, nullptr, sWihF, sWihB, sBihF, sBihB, sxg, 512);
    gru_level<<<2, 512, 0, stream>>>(sWhhF, sWhhB, sBhhF, sBhhB, sxg, sout, 256, 1);
    attn_sent<<<1, 256, 0, stream>>>(sout, sAttW, sAttB, doc);
    classify<<<1, 64, 0, stream>>>(doc, clsW, clsB, (float*)d_out);
}